// Round 6
// baseline (347.214 us; speedup 1.0000x reference)
//
#include <hip/hip_runtime.h>
#include <math.h>

#define NN    8192
#define KF    512
#define DF    64
#define NCH   32
#define EC    136   // E row: [posH 0..63][negH 64..127][onesP 128][onesN 129][pad]
#define GRID  512
#define KSPLIT 4

union SM {
    struct { float xs[32][68]; float wt[32][64]; } g;           // GEMM: 16.9 KB
    struct { unsigned int sk[NN]; int part[256]; } r;           // rank: 33 KB
    struct { float v2s[KF]; } s;                                // s2
    struct { double cOs[8]; double wtot[4][8]; double red[4][8]; } sc;
    float ss[NN];                                               // out: 32 KB
};

__device__ __forceinline__ void gridbar(int* __restrict__ bar, int ph) {
    __syncthreads();
    if (threadIdx.x == 0) {
        __threadfence();
        atomicAdd(&bar[ph], 1);
        while (__hip_atomic_load(&bar[ph], __ATOMIC_RELAXED, __HIP_MEMORY_SCOPE_AGENT) < GRID)
            __builtin_amdgcn_s_sleep(2);
        __threadfence();
    }
    __syncthreads();
}

__device__ __forceinline__ unsigned int f2key(float f) {
    unsigned int u = __float_as_uint(f);
    return u ^ ((u >> 31) ? 0xFFFFFFFFu : 0x80000000u);
}

// col-group: g<8 -> pos h1 cols 8g..; g<16 -> neg h1; g==16 -> ones {128,129}
__device__ __forceinline__ void load_vals(int g, int p, const float* __restrict__ h1,
        const int* __restrict__ order, const double* __restrict__ wpos,
        const double* __restrict__ wneg, double* vals, int& ncols, int& colbase) {
    if (g < 16) {
        ncols = 8;
        const int d0 = (g < 8) ? 8 * g : 8 * (g - 8);
        colbase = (g < 8) ? d0 : 64 + d0;
        const double wgt = (g < 8) ? wpos[p] : wneg[p];
        const float* hp = h1 + (size_t)order[p] * DF + d0;
        const float4 h0 = *reinterpret_cast<const float4*>(hp);
        const float4 h4 = *reinterpret_cast<const float4*>(hp + 4);
        vals[0]=wgt*h0.x; vals[1]=wgt*h0.y; vals[2]=wgt*h0.z; vals[3]=wgt*h0.w;
        vals[4]=wgt*h4.x; vals[5]=wgt*h4.y; vals[6]=wgt*h4.z; vals[7]=wgt*h4.w;
    } else {
        ncols = 2; colbase = 128;
        vals[0] = wpos[p]; vals[1] = wneg[p];
    }
}

__global__ void k_zero(int* bar) { if (threadIdx.x < 8) bar[threadIdx.x] = 0; }

__global__ __launch_bounds__(256, 2) void k_fat(const float* __restrict__ x,
        const float* __restrict__ nmat, const float* __restrict__ W,
        const float* __restrict__ w1, const float* __restrict__ w2,
        float* __restrict__ h1, float* __restrict__ s2,
        int* __restrict__ order, float* __restrict__ s2s,
        double* __restrict__ wpos, double* __restrict__ wneg,
        double* __restrict__ cT, double* __restrict__ E,
        float* __restrict__ hpart, int* __restrict__ bar,
        float* __restrict__ out) {
    __shared__ SM sm;
    const int tid = threadIdx.x;
    const int bid = blockIdx.x;

    // ================= P1: hpart[ks] = x[:,ks] @ Wt (R2-proven 4x4 tile) =====
    {
        const int rb = bid & 127, ks = bid >> 7;
        const int row0 = rb * 64;
        const int kbase = ks * (KF / KSPLIT);
        const int ty = tid >> 4, tx = tid & 15;
        float acc[4][4] = {};
        for (int kc = 0; kc < KF / KSPLIT; kc += 32) {
            const int kk = kbase + kc;
            {
                const int r  = tid >> 3;
                const int c4 = (tid & 7) * 4;
                float4 v0 = *reinterpret_cast<const float4*>(x + (size_t)(row0 + r) * KF + kk + c4);
                float4 v1 = *reinterpret_cast<const float4*>(x + (size_t)(row0 + 32 + r) * KF + kk + c4);
                sm.g.xs[c4+0][r] = v0.x; sm.g.xs[c4+1][r] = v0.y;
                sm.g.xs[c4+2][r] = v0.z; sm.g.xs[c4+3][r] = v0.w;
                sm.g.xs[c4+0][32+r] = v1.x; sm.g.xs[c4+1][32+r] = v1.y;
                sm.g.xs[c4+2][32+r] = v1.z; sm.g.xs[c4+3][32+r] = v1.w;
                // W rows are the 64 output cols; stage [k][d] transposed
                const int wd = tid & 63, wg = tid >> 6;
                float4 wv0 = *reinterpret_cast<const float4*>(W + (size_t)wd * KF + kk + wg * 8);
                float4 wv1 = *reinterpret_cast<const float4*>(W + (size_t)wd * KF + kk + wg * 8 + 4);
                sm.g.wt[wg*8+0][wd]=wv0.x; sm.g.wt[wg*8+1][wd]=wv0.y;
                sm.g.wt[wg*8+2][wd]=wv0.z; sm.g.wt[wg*8+3][wd]=wv0.w;
                sm.g.wt[wg*8+4][wd]=wv1.x; sm.g.wt[wg*8+5][wd]=wv1.y;
                sm.g.wt[wg*8+6][wd]=wv1.z; sm.g.wt[wg*8+7][wd]=wv1.w;
            }
            __syncthreads();
            #pragma unroll 8
            for (int k = 0; k < 32; ++k) {
                const float4 a4 = *reinterpret_cast<const float4*>(&sm.g.xs[k][ty * 4]);
                const float4 b4 = *reinterpret_cast<const float4*>(&sm.g.wt[k][tx * 4]);
                const float av[4] = {a4.x, a4.y, a4.z, a4.w};
                const float bv[4] = {b4.x, b4.y, b4.z, b4.w};
                #pragma unroll
                for (int i = 0; i < 4; ++i)
                    #pragma unroll
                    for (int j = 0; j < 4; ++j)
                        acc[i][j] = fmaf(av[i], bv[j], acc[i][j]);
            }
            __syncthreads();
        }
        float* hp = hpart + (size_t)ks * NN * DF;
        #pragma unroll
        for (int i = 0; i < 4; ++i)
            *reinterpret_cast<float4*>(hp + (size_t)(row0 + ty * 4 + i) * DF + tx * 4) =
                make_float4(acc[i][0], acc[i][1], acc[i][2], acc[i][3]);
    }
    gridbar(bar, 0);

    // ================= P2: blocks 0..255 combine h1; 256..511 s2 =============
    if (bid < 256) {
        const float4* hp4 = reinterpret_cast<const float4*>(hpart);
        float4* h14 = reinterpret_cast<float4*>(h1);
        #pragma unroll
        for (int t = 0; t < 2; ++t) {
            const int f = bid * 512 + t * 256 + tid;
            float4 a = hp4[f];
            #pragma unroll
            for (int s = 1; s < KSPLIT; ++s) {
                const float4 b = hp4[(size_t)s * (NN * DF / 4) + f];
                a.x += b.x; a.y += b.y; a.z += b.z; a.w += b.w;
            }
            h14[f] = a;
        }
    } else {
        float a0 = 0.f, a1 = 0.f;
        for (int d = 0; d < DF; ++d) {
            const float wd2 = w2[d];
            a0 = fmaf(W[(size_t)d * KF + tid],       wd2, a0);
            a1 = fmaf(W[(size_t)d * KF + 256 + tid], wd2, a1);
        }
        sm.s.v2s[tid] = a0; sm.s.v2s[tid + 256] = a1;
        __syncthreads();
        const int lane = tid & 63, w = tid >> 6;
        const float4 b0 = *reinterpret_cast<const float4*>(&sm.s.v2s[lane * 4]);
        const float4 b1 = *reinterpret_cast<const float4*>(&sm.s.v2s[256 + lane * 4]);
        const int row0 = (bid - 256) * 32;
        for (int rr = 0; rr < 8; ++rr) {
            const int row = row0 + w * 8 + rr;
            const float4 n0 = *reinterpret_cast<const float4*>(nmat + (size_t)row * KF + lane * 4);
            const float4 n1 = *reinterpret_cast<const float4*>(nmat + (size_t)row * KF + 256 + lane * 4);
            float acc = n0.x * b0.x;
            acc = fmaf(n0.y, b0.y, acc); acc = fmaf(n0.z, b0.z, acc); acc = fmaf(n0.w, b0.w, acc);
            acc = fmaf(n1.x, b1.x, acc); acc = fmaf(n1.y, b1.y, acc);
            acc = fmaf(n1.z, b1.z, acc); acc = fmaf(n1.w, b1.w, acc);
            #pragma unroll
            for (int off = 32; off; off >>= 1) acc += __shfl_xor(acc, off);
            if (lane == 0) s2[row] = acc;
        }
    }
    gridbar(bar, 1);

    // ================= P3: rank (16 j's per block) ===========================
    {
        {
            const float4* src = reinterpret_cast<const float4*>(s2);
            #pragma unroll
            for (int t = 0; t < 8; ++t) {
                const float4 v = src[tid + t * 256];
                const int b = (tid + t * 256) * 4;
                sm.r.sk[b]   = f2key(v.x); sm.r.sk[b+1] = f2key(v.y);
                sm.r.sk[b+2] = f2key(v.z); sm.r.sk[b+3] = f2key(v.w);
            }
        }
        __syncthreads();
        const int jl = tid & 15, seg = tid >> 4;
        const int j = bid * 16 + jl;
        const unsigned int mk = sm.r.sk[j];
        const int base = seg * 512;
        int cnt = 0;
        for (int q = 0; q < 128; ++q) {
            const int e = (q * 4 + seg * 4) & 511;
            const int idx = base + e;
            const uint4 v = *reinterpret_cast<const uint4*>(&sm.r.sk[idx]);
            cnt += (v.x < mk) | ((v.x == mk) & (idx     < j));
            cnt += (v.y < mk) | ((v.y == mk) & (idx + 1 < j));
            cnt += (v.z < mk) | ((v.z == mk) & (idx + 2 < j));
            cnt += (v.w < mk) | ((v.w == mk) & (idx + 3 < j));
        }
        sm.r.part[tid] = cnt;
        __syncthreads();
        if (tid < 16) {
            int r = 0;
            #pragma unroll
            for (int s = 0; s < 16; ++s) r += sm.r.part[s * 16 + tid];
            const int jj = bid * 16 + tid;
            const float v = s2[jj];
            order[r] = jj;
            s2s[r] = v;
            wpos[r] = exp((double)v);
            wneg[r] = exp(0.2 * (double)v);
        }
    }
    gridbar(bar, 2);

    // ================= P4: per-(colgroup,chunk) totals =======================
    for (int u = bid; u < 17 * NCH; u += GRID) {
        const int g = u >> 5, c = u & 31;
        const int lane = tid & 63, w = tid >> 6;
        const int p = c * 256 + tid;
        double vals[8]; int ncols, colbase;
        load_vals(g, p, h1, order, wpos, wneg, vals, ncols, colbase);
        __syncthreads();   // protect sm.sc reuse across loop iterations
        for (int jj = 0; jj < ncols; ++jj) {
            double r = vals[jj];
            #pragma unroll
            for (int off = 32; off; off >>= 1) r += __shfl_xor(r, off);
            if (lane == 0) sm.sc.red[w][jj] = r;
        }
        __syncthreads();
        if (tid < ncols)
            cT[(size_t)(colbase + tid) * NCH + c] =
                sm.sc.red[0][tid] + sm.sc.red[1][tid] + sm.sc.red[2][tid] + sm.sc.red[3][tid];
    }
    gridbar(bar, 3);

    // ================= P5: exclusive scan -> E ===============================
    for (int u = bid; u < 17 * NCH; u += GRID) {
        const int g = u >> 5, c = u & 31;
        const int lane = tid & 63, w = tid >> 6;
        const int p = c * 256 + tid;
        double vals[8], inc8[8]; int ncols, colbase;
        load_vals(g, p, h1, order, wpos, wneg, vals, ncols, colbase);
        __syncthreads();
        if (tid < ncols) {
            double s = 0.0;
            const double* ct = cT + (size_t)(colbase + tid) * NCH;
            for (int cc = 0; cc < c; ++cc) s += ct[cc];
            sm.sc.cOs[tid] = s;
        }
        for (int jj = 0; jj < ncols; ++jj) {
            double incl = vals[jj];
            #pragma unroll
            for (int off = 1; off < 64; off <<= 1) {
                double t = __shfl_up(incl, off);
                if (lane >= off) incl += t;
            }
            inc8[jj] = incl;
            if (lane == 63) sm.sc.wtot[w][jj] = incl;
        }
        __syncthreads();
        double* Ep = E + (size_t)p * EC + colbase;
        for (int jj = 0; jj < ncols; ++jj) {
            double woff = sm.sc.cOs[jj];
            for (int ww = 0; ww < w; ++ww) woff += sm.sc.wtot[ww][jj];
            Ep[jj] = woff + inc8[jj] - vals[jj];
        }
        if (c == NCH - 1 && tid < ncols)
            E[(size_t)NN * EC + colbase + tid] =
                sm.sc.cOs[tid] + sm.sc.wtot[0][tid] + sm.sc.wtot[1][tid] +
                sm.sc.wtot[2][tid] + sm.sc.wtot[3][tid];
    }
    gridbar(bar, 4);

    // ================= P6: s1 inline + binary search + combine ===============
    {
        {
            const float4* src = reinterpret_cast<const float4*>(s2s);
            float4* dst = reinterpret_cast<float4*>(sm.ss);
            #pragma unroll
            for (int t = 0; t < 8; ++t) dst[tid + t * 256] = src[tid + t * 256];
        }
        __syncthreads();
        const int lane = tid & 63, w = tid >> 6;
        const int i0 = bid * 16 + w * 4;
        const float wl = w1[lane];
        float s1v[4];
        #pragma unroll
        for (int r = 0; r < 4; ++r) {
            float p = h1[(size_t)(i0 + r) * DF + lane] * wl;
            #pragma unroll
            for (int off = 32; off; off >>= 1) p += __shfl_xor(p, off);
            s1v[r] = p;
        }
        int lo[4] = {0, 0, 0, 0}, hi[4] = {NN, NN, NN, NN};
        for (int step = 0; step < 13; ++step) {
            #pragma unroll
            for (int r = 0; r < 4; ++r) {
                const int mid = (lo[r] + hi[r]) >> 1;
                if (sm.ss[mid] < -s1v[r]) lo[r] = mid + 1; else hi[r] = mid;
            }
        }
        const double* Et = E + (size_t)NN * EC;
        #pragma unroll
        for (int r = 0; r < 4; ++r) {
            const double* Ek = E + (size_t)lo[r] * EC;
            const double e1 = exp((double)s1v[r]);
            const double e2 = exp(0.2 * (double)s1v[r]);
            const double num = e1 * (Et[lane] - Ek[lane]) + e2 * Ek[64 + lane];
            const double den = e1 * (Et[128] - Ek[128]) + e2 * Ek[129];
            out[(size_t)(i0 + r) * DF + lane] = (float)(num / den);
        }
    }
}

extern "C" void kernel_launch(void* const* d_in, const int* in_sizes, int n_in,
                              void* d_out, int out_size, void* d_ws, size_t ws_size,
                              hipStream_t stream) {
    const float* x    = (const float*)d_in[0];
    const float* nmat = (const float*)d_in[1];
    const float* W    = (const float*)d_in[2];
    const float* w1   = (const float*)d_in[3];
    const float* w2   = (const float*)d_in[4];
    float* out = (float*)d_out;

    char* ws = (char*)d_ws;
    size_t off = 0;
    auto alloc = [&](size_t bytes) -> void* {
        void* p = ws + off;
        off += (bytes + 255) & ~(size_t)255;
        return p;
    };
    int*    bar   = (int*)alloc(64);
    float*  h1    = (float*)alloc((size_t)NN * DF * 4);        // 2 MB
    float*  s2    = (float*)alloc((size_t)NN * 4);
    int*    order = (int*)alloc((size_t)NN * 4);
    float*  s2s   = (float*)alloc((size_t)NN * 4);
    double* wpos  = (double*)alloc((size_t)NN * 8);
    double* wneg  = (double*)alloc((size_t)NN * 8);
    double* cT    = (double*)alloc((size_t)130 * NCH * 8);
    double* E     = (double*)alloc((size_t)(NN + 1) * EC * 8); // 8.9 MB
    float*  hpart = (float*)E;  // alias: hpart dead before first E write (P5)

    k_zero<<<1, 64, 0, stream>>>(bar);
    k_fat<<<GRID, 256, 0, stream>>>(x, nmat, W, w1, w2, h1, s2, order, s2s,
                                    wpos, wneg, cT, E, hpart, bar, out);
}

// Round 7
// 78.753 us; speedup vs baseline: 4.4089x; 4.4089x over previous
//
#include <hip/hip_runtime.h>
#include <math.h>

#define NN    8192
#define KF    512
#define DF    64
#define NCH   32
#define NCOL  130
#define KSPLIT 4

typedef __attribute__((ext_vector_type(8))) short bf16x8;
typedef __attribute__((ext_vector_type(4))) float f32x4;

__device__ __forceinline__ unsigned short f2bf_rn(float f) {
    unsigned u = __float_as_uint(f);
    unsigned r = (u + 0x7fffu + ((u >> 16) & 1u)) >> 16;
    return (unsigned short)r;
}
__device__ __forceinline__ float bf2f(unsigned short s) {
    return __uint_as_float(((unsigned)s) << 16);
}

// ======== K0: v2 = W^T w2; Wh/Wl = split-bf16 of W (row-major [64][512]) ========
__global__ __launch_bounds__(256) void k_prep(const float* __restrict__ W,
        const float* __restrict__ w2, float* __restrict__ v2,
        unsigned short* __restrict__ Wh, unsigned short* __restrict__ Wl) {
    const int k = blockIdx.x * 256 + threadIdx.x;   // 0..511
    float a2 = 0.f;
    for (int o = 0; o < DF; ++o) {
        const float wv = W[(size_t)o * KF + k];
        a2 = fmaf(wv, w2[o], a2);
        const unsigned short hi = f2bf_rn(wv);
        Wh[(size_t)o * KF + k] = hi;
        Wl[(size_t)o * KF + k] = f2bf_rn(wv - bf2f(hi));
    }
    v2[k] = a2;
}

// ======== K1: hpart[ks] = x[:,ks-slice] @ W^T via split-bf16 MFMA ========
// 512 blocks: rb = bid&127 (64 rows), ks = bid>>7 (K-split of 128).
__global__ __launch_bounds__(256) void k_gemm(const float* __restrict__ x,
        const unsigned short* __restrict__ Wh, const unsigned short* __restrict__ Wl,
        float* __restrict__ hpart) {
    __shared__ unsigned short xh[64][136];   // 17.0 KB, +8 pad keeps 16B align, kills stride-256 conflicts
    __shared__ unsigned short xl[64][136];
    const int tid = threadIdx.x;
    const int rb = blockIdx.x & 127, ks = blockIdx.x >> 7;
    const int row0 = rb * 64, kbase = ks * (KF / KSPLIT);
    // ---- stage x tile (64 rows x 128 k) as bf16 hi/lo
    {
        const int r = tid >> 2, q = tid & 3;
        const float* xr = x + (size_t)(row0 + r) * KF + kbase + q * 32;
        #pragma unroll
        for (int i = 0; i < 8; ++i) {
            const float4 v = *reinterpret_cast<const float4*>(xr + i * 4);
            ushort4 h, l;
            h.x = f2bf_rn(v.x); l.x = f2bf_rn(v.x - bf2f(h.x));
            h.y = f2bf_rn(v.y); l.y = f2bf_rn(v.y - bf2f(h.y));
            h.z = f2bf_rn(v.z); l.z = f2bf_rn(v.z - bf2f(h.z));
            h.w = f2bf_rn(v.w); l.w = f2bf_rn(v.w - bf2f(h.w));
            *reinterpret_cast<ushort4*>(&xh[r][q * 32 + i * 4]) = h;
            *reinterpret_cast<ushort4*>(&xl[r][q * 32 + i * 4]) = l;
        }
    }
    __syncthreads();
    // ---- MFMA: wave w owns rows w*16..w*16+15; 4 col-groups of 16
    const int w = tid >> 6, l = tid & 63;
    const int fr = l & 15, fq = l >> 4;
    f32x4 acc[4] = {{0.f,0.f,0.f,0.f},{0.f,0.f,0.f,0.f},{0.f,0.f,0.f,0.f},{0.f,0.f,0.f,0.f}};
    #pragma unroll
    for (int kstep = 0; kstep < 4; ++kstep) {
        const int k0 = kstep * 32;
        const bf16x8 ah = *reinterpret_cast<const bf16x8*>(&xh[w * 16 + fr][k0 + fq * 8]);
        const bf16x8 al = *reinterpret_cast<const bf16x8*>(&xl[w * 16 + fr][k0 + fq * 8]);
        #pragma unroll
        for (int cg = 0; cg < 4; ++cg) {
            const size_t wb = (size_t)(cg * 16 + fr) * KF + kbase + k0 + fq * 8;
            const bf16x8 bh = *reinterpret_cast<const bf16x8*>(Wh + wb);
            const bf16x8 bl = *reinterpret_cast<const bf16x8*>(Wl + wb);
            acc[cg] = __builtin_amdgcn_mfma_f32_16x16x32_bf16(ah, bh, acc[cg], 0, 0, 0);
            acc[cg] = __builtin_amdgcn_mfma_f32_16x16x32_bf16(al, bh, acc[cg], 0, 0, 0);
            acc[cg] = __builtin_amdgcn_mfma_f32_16x16x32_bf16(ah, bl, acc[cg], 0, 0, 0);
        }
    }
    // ---- store: D col = lane&15, row = (lane>>4)*4 + reg
    float* hp = hpart + (size_t)ks * NN * DF;
    #pragma unroll
    for (int cg = 0; cg < 4; ++cg)
        #pragma unroll
        for (int j = 0; j < 4; ++j)
            hp[(size_t)(row0 + w * 16 + fq * 4 + j) * DF + cg * 16 + fr] = acc[cg][j];
}

// ======== K1b: h1 = sum_s hpart[s]; s1 = h1 @ w_att1 ========
__global__ __launch_bounds__(256) void k_combine(const float* __restrict__ hpart,
        const float* __restrict__ w_att1, float* __restrict__ h1, float* __restrict__ s1) {
    const int lane = threadIdx.x & 63, wave = threadIdx.x >> 6;
    const int row = blockIdx.x * 4 + wave;
    float v = 0.f;
    #pragma unroll
    for (int s = 0; s < KSPLIT; ++s) v += hpart[((size_t)s * NN + row) * DF + lane];
    h1[(size_t)row * DF + lane] = v;
    float p = v * w_att1[lane];
    #pragma unroll
    for (int off = 32; off; off >>= 1) p += __shfl_xor(p, off);
    if (lane == 0) s1[row] = p;
}

// ======== K2: s2 = n @ v2 (one wave per row) ========
__global__ __launch_bounds__(256) void k_s2(const float* __restrict__ n,
        const float* __restrict__ v2, float* __restrict__ s2) {
    const int lane = threadIdx.x & 63;
    const int row = (blockIdx.x * 256 + threadIdx.x) >> 6;
    const float4* a = reinterpret_cast<const float4*>(n + (size_t)row * KF);
    const float4* b = reinterpret_cast<const float4*>(v2);
    float acc = 0.f;
    #pragma unroll
    for (int c = 0; c < 2; ++c) {
        float4 av = a[lane + c * 64], bv = b[lane + c * 64];
        acc = fmaf(av.x, bv.x, fmaf(av.y, bv.y, fmaf(av.z, bv.z, fmaf(av.w, bv.w, acc))));
    }
    #pragma unroll
    for (int off = 32; off; off >>= 1) acc += __shfl_xor(acc, off);
    if (lane == 0) s2[row] = acc;
}

// ======== K3: brute-force rank, 2D tiled partial counts ========
__global__ __launch_bounds__(256) void k_count(const float* __restrict__ s2,
                                               int* __restrict__ partial) {
    __shared__ float sk[256];
    const int j = blockIdx.x * 256 + threadIdx.x;
    const int k0 = blockIdx.y * 256;
    sk[threadIdx.x] = s2[k0 + threadIdx.x];
    __syncthreads();
    const float mine = s2[j];
    int cnt = 0;
    #pragma unroll 8
    for (int t = 0; t < 256; ++t) {
        float v = sk[t];
        int idx = k0 + t;
        cnt += (v < mine) || (v == mine && idx < j);
    }
    partial[(size_t)blockIdx.y * NN + j] = cnt;
}

// ======== K4: reduce ranks + scatter sorted arrays + exp weights ========
__global__ __launch_bounds__(256) void k_scatter(const float* __restrict__ s2,
        const int* __restrict__ partial, int* __restrict__ order,
        float* __restrict__ s2s, double* __restrict__ wpos, double* __restrict__ wneg) {
    const int j = blockIdx.x * 256 + threadIdx.x;
    int r = 0;
    for (int kb = 0; kb < NCH; ++kb) r += partial[(size_t)kb * NN + j];
    const float v = s2[j];
    order[r] = j;
    s2s[r] = v;
    wpos[r] = exp((double)v);
    wneg[r] = exp(0.2 * (double)v);
}

// ======== K5: per-chunk totals ========
__global__ __launch_bounds__(256) void k_chunksum(const float* __restrict__ h1,
        const int* __restrict__ order, const double* __restrict__ wpos,
        const double* __restrict__ wneg, double* __restrict__ cT) {
    __shared__ double red[256];
    const int col = blockIdx.x >> 5, c = blockIdx.x & 31;
    const int p = c * 256 + threadIdx.x;
    const double wgt = (col < 65) ? wpos[p] : wneg[p];
    const int d = (col < 65) ? col : col - 65;
    double val = (d < DF) ? wgt * (double)h1[(size_t)order[p] * DF + d] : wgt;
    red[threadIdx.x] = val;
    __syncthreads();
    for (int s = 128; s; s >>= 1) {
        if (threadIdx.x < s) red[threadIdx.x] += red[threadIdx.x + s];
        __syncthreads();
    }
    if (threadIdx.x == 0) cT[blockIdx.x] = red[0];
}

// ======== K6: scan chunk totals per column; write grand totals row ========
__global__ void k_chunkscan(const double* __restrict__ cT, double* __restrict__ cO,
                            double* __restrict__ E) {
    const int col = threadIdx.x;
    if (col >= NCOL) return;
    double run = 0.0;
    for (int c = 0; c < NCH; ++c) {
        cO[(size_t)col * NCH + c] = run;
        run += cT[(size_t)col * NCH + c];
    }
    E[(size_t)NN * NCOL + col] = run;
}

// ======== K7: per-chunk exclusive scan + chunk offset -> E ========
__global__ __launch_bounds__(256) void k_scan(const float* __restrict__ h1,
        const int* __restrict__ order, const double* __restrict__ wpos,
        const double* __restrict__ wneg, const double* __restrict__ cO,
        double* __restrict__ E) {
    __shared__ double buf[2][256];
    const int col = blockIdx.x >> 5, c = blockIdx.x & 31;
    const int tid = threadIdx.x;
    const int p = c * 256 + tid;
    const double wgt = (col < 65) ? wpos[p] : wneg[p];
    const int d = (col < 65) ? col : col - 65;
    double val = (d < DF) ? wgt * (double)h1[(size_t)order[p] * DF + d] : wgt;
    buf[0][tid] = val;
    int cur = 0;
    for (int off = 1; off < 256; off <<= 1) {
        __syncthreads();
        double t = buf[cur][tid];
        if (tid >= off) t += buf[cur][tid - off];
        buf[cur ^ 1][tid] = t;
        cur ^= 1;
    }
    __syncthreads();
    const double excl = tid ? buf[cur][tid - 1] : 0.0;
    E[(size_t)p * NCOL + col] = cO[blockIdx.x] + excl;
}

// ======== K8: per-row binary search + combine ========
__global__ __launch_bounds__(256) void k_out(const float* __restrict__ s1,
        const float* __restrict__ s2s, const double* __restrict__ E,
        float* __restrict__ out) {
    const int lane = threadIdx.x & 63, wave = threadIdx.x >> 6;
    const int i = blockIdx.x * 4 + wave;
    const float s1v = s1[i];
    const float t = -s1v;
    int lo = 0, hi = NN;
    while (lo < hi) {
        int mid = (lo + hi) >> 1;
        if (s2s[mid] < t) lo = mid + 1; else hi = mid;
    }
    const double* Ek = E + (size_t)lo * NCOL;
    const double* Et = E + (size_t)NN * NCOL;
    const double e1 = exp((double)s1v);
    const double e2 = exp(0.2 * (double)s1v);
    const double num = e1 * (Et[lane] - Ek[lane]) + e2 * Ek[65 + lane];
    const double den = e1 * (Et[DF] - Ek[DF]) + e2 * Ek[65 + DF];
    out[(size_t)i * DF + lane] = (float)(num / den);
}

extern "C" void kernel_launch(void* const* d_in, const int* in_sizes, int n_in,
                              void* d_out, int out_size, void* d_ws, size_t ws_size,
                              hipStream_t stream) {
    const float* x    = (const float*)d_in[0];
    const float* nmat = (const float*)d_in[1];
    const float* W    = (const float*)d_in[2];
    const float* w1   = (const float*)d_in[3];
    const float* w2   = (const float*)d_in[4];
    float* out = (float*)d_out;

    char* ws = (char*)d_ws;
    size_t off = 0;
    auto alloc = [&](size_t bytes) -> void* {
        void* p = ws + off;
        off += (bytes + 255) & ~(size_t)255;
        return p;
    };
    unsigned short* Wh = (unsigned short*)alloc((size_t)DF * KF * 2);   // 64 KB
    unsigned short* Wl = (unsigned short*)alloc((size_t)DF * KF * 2);   // 64 KB
    float*  v2      = (float*)alloc((size_t)KF * 4);
    float*  h1      = (float*)alloc((size_t)NN * DF * 4);               // 2 MB
    float*  s1      = (float*)alloc((size_t)NN * 4);
    float*  s2      = (float*)alloc((size_t)NN * 4);
    int*    partial = (int*)alloc((size_t)NCH * NN * 4);                // 1 MB
    int*    order   = (int*)alloc((size_t)NN * 4);
    float*  s2s     = (float*)alloc((size_t)NN * 4);
    double* wpos    = (double*)alloc((size_t)NN * 8);
    double* wneg    = (double*)alloc((size_t)NN * 8);
    double* cT      = (double*)alloc((size_t)NCOL * NCH * 8);
    double* cO      = (double*)alloc((size_t)NCOL * NCH * 8);
    double* E       = (double*)alloc((size_t)(NN + 1) * NCOL * 8);      // 8.52 MB
    // hpart (4 * 2 MB = 8 MB) aliases E[0 .. NN*NCOL): hpart dead after k_combine;
    // E's body is first written by k_scan, grand-total row (offset 8.52 MB-end) by
    // k_chunkscan — both after k_combine. 8 MB < NN*NCOL*8 = 8.519 MB. OK.
    float*  hpart   = (float*)E;

    k_prep<<<2, 256, 0, stream>>>(W, w2, v2, Wh, Wl);
    k_gemm<<<512, 256, 0, stream>>>(x, Wh, Wl, hpart);
    k_combine<<<NN / 4, 256, 0, stream>>>(hpart, w1, h1, s1);
    k_s2<<<NN / 4, 256, 0, stream>>>(nmat, v2, s2);
    k_count<<<dim3(NCH, NCH), 256, 0, stream>>>(s2, partial);
    k_scatter<<<NCH, 256, 0, stream>>>(s2, partial, order, s2s, wpos, wneg);
    k_chunksum<<<NCOL * NCH, 256, 0, stream>>>(h1, order, wpos, wneg, cT);
    k_chunkscan<<<1, 256, 0, stream>>>(cT, cO, E);
    k_scan<<<NCOL * NCH, 256, 0, stream>>>(h1, order, wpos, wneg, cO, E);
    k_out<<<NN / 4, 256, 0, stream>>>(s1, s2s, E, out);
}